// Round 9
// baseline (531.296 us; speedup 1.0000x reference)
//
#include <hip/hip_runtime.h>

static constexpr int T_STEPS = 512;
static constexpr int NBATCH  = 256;
static constexpr int DD      = 128;                         // C = D = K = 128
static constexpr long TND    = (long)T_STEPS * NBATCH * DD; // elems per output tensor

typedef short bf16x8 __attribute__((ext_vector_type(8)));   // 8 bf16 in 4 VGPRs
typedef float f32x4  __attribute__((ext_vector_type(4)));
typedef unsigned u32x4 __attribute__((ext_vector_type(4)));

__device__ inline unsigned short f2bf(float f) {            // RNE fp32 -> bf16
  unsigned u = __builtin_bit_cast(unsigned, f);
  unsigned r = u + 0x7FFFu + ((u >> 16) & 1u);
  return (unsigned short)(r >> 16);
}

__device__ inline bf16x8 pack8(const float* s) {
  bf16x8 v;
#pragma unroll
  for (int i = 0; i < 8; ++i) v[i] = (short)f2bf(s[i]);
  return v;
}

// v_cvt_pk_bf16_f32: D.lo = bf16(lo), D.hi = bf16(hi), RNE (gfx950).
__device__ __forceinline__ unsigned cvtpk_bf16(float lo, float hi) {
  unsigned r;
  asm("v_cvt_pk_bf16_f32 %0, %1, %2" : "=v"(r) : "v"(lo), "v"(hi));
  return r;
}

// ---------------------------------------------------------------------------
// Pre-pass: x (f32, 64MB) -> bf16 (32MB), RNE. Output parked in the Y region
// (overwritten by GEMM-Y only after the scan consumed it, same stream).
// ---------------------------------------------------------------------------
__global__ __launch_bounds__(256) void cvt_x_bf16(
    const float* __restrict__ x, unsigned short* __restrict__ xb, long n8) {
  long i = (long)blockIdx.x * 256 + threadIdx.x;
  const long stride = (long)gridDim.x * 256;
  for (; i < n8; i += stride) {
    const float* p = x + i * 8;
    f32x4 a = *(const f32x4*)p, b = *(const f32x4*)(p + 4);
    u32x4 u;
    u[0] = cvtpk_bf16(a[0], a[1]); u[1] = cvtpk_bf16(a[2], a[3]);
    u[2] = cvtpk_bf16(b[0], b[1]); u[3] = cvtpk_bf16(b[2], b[3]);
    *(u32x4*)(xb + i * 8) = u;
  }
}

// ---------------------------------------------------------------------------
// Phase 3: Y[M x 128] = A[M x 128] @ Wy^T + by, Wy as the A-operand so the
// D-layout gives per-lane contiguous k -> 8 f32x4 stores/tile. Bias = C-init.
// Staging pack now uses v_cvt_pk (2 elems/inst) instead of scalar f2bf.
// ---------------------------------------------------------------------------
__global__ __launch_bounds__(256) void gemm128_yT(
    const float* __restrict__ A, const float* __restrict__ W,
    const float* __restrict__ bias, float* __restrict__ O, int ntiles) {
  const int lane = threadIdx.x & 63;
  const int wib  = threadIdx.x >> 6;     // wave in block (0..3)
  const int m    = lane & 15;
  const int q    = lane >> 4;

  bf16x8 Wf[8][4];
#pragma unroll
  for (int j = 0; j < 8; ++j)
#pragma unroll
    for (int kq = 0; kq < 4; ++kq) {
      const float* p = W + (j * 16 + m) * DD + kq * 32 + q * 8;
      float t[8];
      *(float4*)&t[0] = *(const float4*)p;
      *(float4*)&t[4] = *(const float4*)(p + 4);
      Wf[j][kq] = pack8(t);
    }
  f32x4 bv4[8];
#pragma unroll
  for (int j = 0; j < 8; ++j) bv4[j] = *(const f32x4*)(bias + j * 16 + 4 * q);

  const int wglobal = blockIdx.x * 4 + wib;
  const int nwaves  = gridDim.x * 4;
#pragma unroll 2
  for (int tile = wglobal; tile < ntiles; tile += nwaves) {
    const long r0 = (long)tile * 16;

    bf16x8 af[4];
#pragma unroll
    for (int kq = 0; kq < 4; ++kq) {
      const float* p = A + (r0 + m) * DD + kq * 32 + q * 8;
      f32x4 lo = *(const f32x4*)p, hi = *(const f32x4*)(p + 4);
      u32x4 u;
      u[0] = cvtpk_bf16(lo[0], lo[1]); u[1] = cvtpk_bf16(lo[2], lo[3]);
      u[2] = cvtpk_bf16(hi[0], hi[1]); u[3] = cvtpk_bf16(hi[2], hi[3]);
      af[kq] = __builtin_bit_cast(bf16x8, u);
    }
    f32x4 acc[8];
#pragma unroll
    for (int j = 0; j < 8; ++j)
      acc[j] = __builtin_amdgcn_mfma_f32_16x16x32_bf16(Wf[j][0], af[0], bv4[j], 0, 0, 0);
#pragma unroll
    for (int kq = 1; kq < 4; ++kq)
#pragma unroll
      for (int j = 0; j < 8; ++j)
        acc[j] = __builtin_amdgcn_mfma_f32_16x16x32_bf16(Wf[j][kq], af[kq], acc[j], 0, 0, 0);

    float* op = O + (r0 + m) * DD + 4 * q;
#pragma unroll
    for (int j = 0; j < 8; ++j)
      *(f32x4*)(op + j * 16) = acc[j];
  }
}

// ---------------------------------------------------------------------------
// Phase 1+2 FUSED scan, v6: 4-wave d-split (R8, verified) + PARALLEL PARTIAL
// ACCUMULATOR CHAINS. R8's residual 1450cy/step back-solves to ~60cy
// dependent-MFMA latency on an 8-deep chain; splitting each output j into
// four depth-2 chains (Wx: bias-init + zero-init; Wh: 2x zero-init) and
// combining with a 2-deep v_add tree cuts the post-e-read critical path to
// ~2 MFMA + adds. Global h-store moved AFTER the barrier (issues under the
// next step's e-read shadow). Exchange (kappa layout, parity-double-buffered,
// one barrier/step, lgkmcnt(0)-only drain) unchanged from R8.
// ---------------------------------------------------------------------------
__global__ __launch_bounds__(256, 1) void rnn_scan_fused(
    const unsigned short* __restrict__ xbf, const float* __restrict__ Wx,
    const float* __restrict__ bx, const float* __restrict__ Wh,
    float* __restrict__ H /* [T][N][128] output: all_h */) {
  __shared__ __align__(16) u32x4 xchg[2][4][64];   // 8KB h-exchange, 2 parities

  const int wv   = threadIdx.x >> 6;   // wave 0..3 owns j = {2wv, 2wv+1}
  const int lane = threadIdx.x & 63;
  const int m = lane & 15;             // batch row within the block's 16
  const int q = lane >> 4;             // quad

  xchg[1][wv][lane] = (u32x4){0u, 0u, 0u, 0u};   // step 0 reads parity 1: h_-1=0
  __syncthreads();

  const int jj0 = 2 * wv;

  // Wx A-frags (standard slot k = 32kq + 8q + s), own j's only
  bf16x8 Wxf[2][4];
#pragma unroll
  for (int jl = 0; jl < 2; ++jl)
#pragma unroll
    for (int kq = 0; kq < 4; ++kq) {
      const float* p = Wx + ((jj0 + jl) * 16 + m) * DD + kq * 32 + q * 8;
      float t[8];
      *(float4*)&t[0] = *(const float4*)p;
      *(float4*)&t[4] = *(const float4*)(p + 4);
      Wxf[jl][kq] = pack8(t);
    }
  // Wh A-frags with the q-dependent kappa gather, own j's only
  bf16x8 Whf[2][4];
#pragma unroll
  for (int jl = 0; jl < 2; ++jl)
#pragma unroll
    for (int kq = 0; kq < 4; ++kq) {
      const float* p = Wh + ((jj0 + jl) * 16 + m) * DD + kq * 32 + 4 * q;
      float t[8];
      *(float4*)&t[0] = *(const float4*)p;
      *(float4*)&t[4] = *(const float4*)(p + 16);
      Whf[jl][kq] = pack8(t);
    }
  f32x4 bxv[2];
#pragma unroll
  for (int jl = 0; jl < 2; ++jl)
    bxv[jl] = *(const f32x4*)(bx + (jj0 + jl) * 16 + 4 * q);

  const long stepN = (long)NBATCH * DD;
  const unsigned short* xb = xbf + (long)(blockIdx.x * 16 + m) * DD + 8 * q;
  float* hb = H + (long)(blockIdx.x * 16 + m) * DD;

  auto pref = [&](bf16x8 (&r)[4], int t) {     // 4 x 16B ready-to-use B-frags
    const unsigned short* p = xb + (long)t * stepN;
#pragma unroll
    for (int kq = 0; kq < 4; ++kq) r[kq] = *(const bf16x8*)(p + 32 * kq);
  };

  const f32x4 zz = (f32x4){0.f, 0.f, 0.f, 0.f};

  auto step = [&](const bf16x8 (&xf)[4], int t, int par) {
    // exchange reads (written by all waves at step t-1, parity par^1);
    // e[kq] IS bf[kq] — zero repack thanks to the kappa layout.
    bf16x8 b0 = __builtin_bit_cast(bf16x8, xchg[par ^ 1][0][lane]);
    bf16x8 b1 = __builtin_bit_cast(bf16x8, xchg[par ^ 1][1][lane]);
    bf16x8 b2 = __builtin_bit_cast(bf16x8, xchg[par ^ 1][2][lane]);
    bf16x8 b3 = __builtin_bit_cast(bf16x8, xchg[par ^ 1][3][lane]);

    // Wx partial chains (depth 2, start immediately: xf already in regs)
    f32x4 x0a = __builtin_amdgcn_mfma_f32_16x16x32_bf16(Wxf[0][0], xf[0], bxv[0], 0, 0, 0);
    f32x4 x1a = __builtin_amdgcn_mfma_f32_16x16x32_bf16(Wxf[1][0], xf[0], bxv[1], 0, 0, 0);
    f32x4 x0b = __builtin_amdgcn_mfma_f32_16x16x32_bf16(Wxf[0][2], xf[2], zz, 0, 0, 0);
    f32x4 x1b = __builtin_amdgcn_mfma_f32_16x16x32_bf16(Wxf[1][2], xf[2], zz, 0, 0, 0);
    x0a = __builtin_amdgcn_mfma_f32_16x16x32_bf16(Wxf[0][1], xf[1], x0a, 0, 0, 0);
    x1a = __builtin_amdgcn_mfma_f32_16x16x32_bf16(Wxf[1][1], xf[1], x1a, 0, 0, 0);
    x0b = __builtin_amdgcn_mfma_f32_16x16x32_bf16(Wxf[0][3], xf[3], x0b, 0, 0, 0);
    x1b = __builtin_amdgcn_mfma_f32_16x16x32_bf16(Wxf[1][3], xf[3], x1b, 0, 0, 0);
    // Wh partial chains (depth 2, start once e-reads land)
    f32x4 h0a = __builtin_amdgcn_mfma_f32_16x16x32_bf16(Whf[0][0], b0, zz, 0, 0, 0);
    f32x4 h1a = __builtin_amdgcn_mfma_f32_16x16x32_bf16(Whf[1][0], b0, zz, 0, 0, 0);
    f32x4 h0b = __builtin_amdgcn_mfma_f32_16x16x32_bf16(Whf[0][2], b2, zz, 0, 0, 0);
    f32x4 h1b = __builtin_amdgcn_mfma_f32_16x16x32_bf16(Whf[1][2], b2, zz, 0, 0, 0);
    h0a = __builtin_amdgcn_mfma_f32_16x16x32_bf16(Whf[0][1], b1, h0a, 0, 0, 0);
    h1a = __builtin_amdgcn_mfma_f32_16x16x32_bf16(Whf[1][1], b1, h1a, 0, 0, 0);
    h0b = __builtin_amdgcn_mfma_f32_16x16x32_bf16(Whf[0][3], b3, h0b, 0, 0, 0);
    h1b = __builtin_amdgcn_mfma_f32_16x16x32_bf16(Whf[1][3], b3, h1b, 0, 0, 0);

    // combine (2-deep add tree), relu
    f32x4 s0 = (x0a + x0b) + (h0a + h0b);
    f32x4 s1 = (x1a + x1b) + (h1a + h1b);
    f32x4 h0, h1;
#pragma unroll
    for (int r = 0; r < 4; ++r) { h0[r] = fmaxf(s0[r], 0.f); h1[r] = fmaxf(s1[r], 0.f); }

    // publish exchange slice (critical path), then barrier
    u32x4 own;
    own[0] = cvtpk_bf16(h0[0], h0[1]); own[1] = cvtpk_bf16(h0[2], h0[3]);
    own[2] = cvtpk_bf16(h1[0], h1[1]); own[3] = cvtpk_bf16(h1[2], h1[3]);
    xchg[par][wv][lane] = own;

    asm volatile("s_waitcnt lgkmcnt(0)" ::: "memory");  // ds_write visible; NO vmcnt drain
    __builtin_amdgcn_s_barrier();
    __builtin_amdgcn_sched_barrier(0);                  // pin next step's e-reads after barrier

    // global h-store AFTER the barrier: fire-and-forget under the next
    // step's e-read shadow, off the exchange critical path
    float* hp = hb + (long)t * stepN;
    *(f32x4*)(hp + (jj0 + 0) * 16 + 4 * q) = h0;
    *(f32x4*)(hp + (jj0 + 1) * 16 + 4 * q) = h1;
  };

  bf16x8 rA[4], rB[4], rC[4], rD[4];   // 4-deep named x prefetch ring
  pref(rA, 0); pref(rB, 1); pref(rC, 2); pref(rD, 3);

#pragma unroll 1
  for (int t = 0; t < T_STEPS; t += 4) {
    step(rA, t, 0);     pref(rA, t + 4 < T_STEPS ? t + 4 : T_STEPS - 1);
    step(rB, t + 1, 1); pref(rB, t + 5 < T_STEPS ? t + 5 : T_STEPS - 1);
    step(rC, t + 2, 0); pref(rC, t + 6 < T_STEPS ? t + 6 : T_STEPS - 1);
    step(rD, t + 3, 1); pref(rD, t + 7 < T_STEPS ? t + 7 : T_STEPS - 1);
  }
}

// ---------------------------------------------------------------------------
extern "C" void kernel_launch(void* const* d_in, const int* in_sizes, int n_in,
                              void* d_out, int out_size, void* d_ws, size_t ws_size,
                              hipStream_t stream) {
  const float* x  = (const float*)d_in[0];   // (T,N,C)
  const float* Wx = (const float*)d_in[1];   // (D,C)
  const float* bx = (const float*)d_in[2];   // (D)
  const float* Wh = (const float*)d_in[3];   // (D,D)
  const float* Wy = (const float*)d_in[4];   // (K,D)
  const float* by = (const float*)d_in[5];   // (K)

  float* Y = (float*)d_out;        // all_y: [T][N][K]
  float* H = (float*)d_out + TND;  // all_h: [T][N][D]

  // bf16 x staging lives in the Y region (32MB in 64MB); GEMM-Y overwrites
  // it only after the scan has fully consumed it (same-stream ordering).
  unsigned short* xbf = (unsigned short*)Y;

  const int ntiles = T_STEPS * NBATCH / 16;  // 8192 row-tiles

  cvt_x_bf16<<<2048, 256, 0, stream>>>(x, xbf, TND / 8);               // x -> bf16
  rnn_scan_fused<<<NBATCH / 16, 256, 0, stream>>>(xbf, Wx, bx, Wh, H); // -> all_h
  gemm128_yT<<<512, 256, 0, stream>>>(H, Wy, by, Y, ntiles);           // -> all_y
}

// Round 10
// 474.949 us; speedup vs baseline: 1.1186x; 1.1186x over previous
//
#include <hip/hip_runtime.h>

static constexpr int T_STEPS = 512;
static constexpr int NBATCH  = 256;
static constexpr int DD      = 128;                         // C = D = K = 128
static constexpr long TND    = (long)T_STEPS * NBATCH * DD; // elems per output tensor

typedef short bf16x8 __attribute__((ext_vector_type(8)));   // 8 bf16 in 4 VGPRs
typedef float f32x4  __attribute__((ext_vector_type(4)));
typedef unsigned u32x4 __attribute__((ext_vector_type(4)));

__device__ inline unsigned short f2bf(float f) {            // RNE fp32 -> bf16
  unsigned u = __builtin_bit_cast(unsigned, f);
  unsigned r = u + 0x7FFFu + ((u >> 16) & 1u);
  return (unsigned short)(r >> 16);
}

__device__ inline bf16x8 pack8(const float* s) {
  bf16x8 v;
#pragma unroll
  for (int i = 0; i < 8; ++i) v[i] = (short)f2bf(s[i]);
  return v;
}

// v_cvt_pk_bf16_f32: D.lo = bf16(lo), D.hi = bf16(hi), RNE (gfx950).
__device__ __forceinline__ unsigned cvtpk_bf16(float lo, float hi) {
  unsigned r;
  asm("v_cvt_pk_bf16_f32 %0, %1, %2" : "=v"(r) : "v"(lo), "v"(hi));
  return r;
}

// ---------------------------------------------------------------------------
// Pre-pass: x (f32, 64MB) -> bf16 (32MB), RNE. Output parked in the Y region
// (overwritten by GEMM-Y only after the scan consumed it, same stream).
// ---------------------------------------------------------------------------
__global__ __launch_bounds__(256) void cvt_x_bf16(
    const float* __restrict__ x, unsigned short* __restrict__ xb, long n8) {
  long i = (long)blockIdx.x * 256 + threadIdx.x;
  const long stride = (long)gridDim.x * 256;
  for (; i < n8; i += stride) {
    const float* p = x + i * 8;
    f32x4 a = *(const f32x4*)p, b = *(const f32x4*)(p + 4);
    u32x4 u;
    u[0] = cvtpk_bf16(a[0], a[1]); u[1] = cvtpk_bf16(a[2], a[3]);
    u[2] = cvtpk_bf16(b[0], b[1]); u[3] = cvtpk_bf16(b[2], b[3]);
    *(u32x4*)(xb + i * 8) = u;
  }
}

// ---------------------------------------------------------------------------
// Phase 3: Y[M x 128] = A[M x 128] @ Wy^T + by, Wy as the A-operand so the
// D-layout gives per-lane contiguous k -> 8 f32x4 stores/tile. Bias = C-init.
// (Frozen from R9 for attribution.)
// ---------------------------------------------------------------------------
__global__ __launch_bounds__(256) void gemm128_yT(
    const float* __restrict__ A, const float* __restrict__ W,
    const float* __restrict__ bias, float* __restrict__ O, int ntiles) {
  const int lane = threadIdx.x & 63;
  const int wib  = threadIdx.x >> 6;     // wave in block (0..3)
  const int m    = lane & 15;
  const int q    = lane >> 4;

  bf16x8 Wf[8][4];
#pragma unroll
  for (int j = 0; j < 8; ++j)
#pragma unroll
    for (int kq = 0; kq < 4; ++kq) {
      const float* p = W + (j * 16 + m) * DD + kq * 32 + q * 8;
      float t[8];
      *(float4*)&t[0] = *(const float4*)p;
      *(float4*)&t[4] = *(const float4*)(p + 4);
      Wf[j][kq] = pack8(t);
    }
  f32x4 bv4[8];
#pragma unroll
  for (int j = 0; j < 8; ++j) bv4[j] = *(const f32x4*)(bias + j * 16 + 4 * q);

  const int wglobal = blockIdx.x * 4 + wib;
  const int nwaves  = gridDim.x * 4;
#pragma unroll 2
  for (int tile = wglobal; tile < ntiles; tile += nwaves) {
    const long r0 = (long)tile * 16;

    bf16x8 af[4];
#pragma unroll
    for (int kq = 0; kq < 4; ++kq) {
      const float* p = A + (r0 + m) * DD + kq * 32 + q * 8;
      f32x4 lo = *(const f32x4*)p, hi = *(const f32x4*)(p + 4);
      u32x4 u;
      u[0] = cvtpk_bf16(lo[0], lo[1]); u[1] = cvtpk_bf16(lo[2], lo[3]);
      u[2] = cvtpk_bf16(hi[0], hi[1]); u[3] = cvtpk_bf16(hi[2], hi[3]);
      af[kq] = __builtin_bit_cast(bf16x8, u);
    }
    f32x4 acc[8];
#pragma unroll
    for (int j = 0; j < 8; ++j)
      acc[j] = __builtin_amdgcn_mfma_f32_16x16x32_bf16(Wf[j][0], af[0], bv4[j], 0, 0, 0);
#pragma unroll
    for (int kq = 1; kq < 4; ++kq)
#pragma unroll
      for (int j = 0; j < 8; ++j)
        acc[j] = __builtin_amdgcn_mfma_f32_16x16x32_bf16(Wf[j][kq], af[kq], acc[j], 0, 0, 0);

    float* op = O + (r0 + m) * DD + 4 * q;
#pragma unroll
    for (int j = 0; j < 8; ++j)
      *(f32x4*)(op + j * 16) = acc[j];
  }
}

// ---------------------------------------------------------------------------
// Phase 1+2 FUSED scan, v7: 4-wave d-split (R8) + SOFTWARE-PIPELINED Wx.
// R9 falsified the dep-chain theory (8->2 chain: no change), leaving the
// per-step sync segment (e-read + lgkm + 4-wave barrier, all waves lockstep)
// as the residual by elimination. v7 moves all h-INDEPENDENT work — the
// global h-store and the 8 Wx MFMAs for step t+1 — into the post-barrier
// shadow, so the serial path is only: e-read -> Wh(depth2) -> combine with
// CARRIED xw -> relu/cvtpk -> ds_write -> lgkm -> barrier.
// Slot discipline: iter t consumes the named slot holding x_{t+1} for the
// shadow xw, then refills it with x_{t+5} (4-step lead, rule #20 static).
// Combine order identical to R9: (x0a+x0b)+(h0a+h0b) -> bitwise-same output.
// ---------------------------------------------------------------------------
__global__ __launch_bounds__(256, 1) void rnn_scan_fused(
    const unsigned short* __restrict__ xbf, const float* __restrict__ Wx,
    const float* __restrict__ bx, const float* __restrict__ Wh,
    float* __restrict__ H /* [T][N][128] output: all_h */) {
  __shared__ __align__(16) u32x4 xchg[2][4][64];   // 8KB h-exchange, 2 parities

  const int wv   = threadIdx.x >> 6;   // wave 0..3 owns j = {2wv, 2wv+1}
  const int lane = threadIdx.x & 63;
  const int m = lane & 15;             // batch row within the block's 16
  const int q = lane >> 4;             // quad

  xchg[1][wv][lane] = (u32x4){0u, 0u, 0u, 0u};   // step 0 reads parity 1: h_-1=0
  __syncthreads();

  const int jj0 = 2 * wv;

  // Wx A-frags (standard slot k = 32kq + 8q + s), own j's only
  bf16x8 Wxf[2][4];
#pragma unroll
  for (int jl = 0; jl < 2; ++jl)
#pragma unroll
    for (int kq = 0; kq < 4; ++kq) {
      const float* p = Wx + ((jj0 + jl) * 16 + m) * DD + kq * 32 + q * 8;
      float t[8];
      *(float4*)&t[0] = *(const float4*)p;
      *(float4*)&t[4] = *(const float4*)(p + 4);
      Wxf[jl][kq] = pack8(t);
    }
  // Wh A-frags with the q-dependent kappa gather, own j's only
  bf16x8 Whf[2][4];
#pragma unroll
  for (int jl = 0; jl < 2; ++jl)
#pragma unroll
    for (int kq = 0; kq < 4; ++kq) {
      const float* p = Wh + ((jj0 + jl) * 16 + m) * DD + kq * 32 + 4 * q;
      float t[8];
      *(float4*)&t[0] = *(const float4*)p;
      *(float4*)&t[4] = *(const float4*)(p + 16);
      Whf[jl][kq] = pack8(t);
    }
  f32x4 bxv[2];
#pragma unroll
  for (int jl = 0; jl < 2; ++jl)
    bxv[jl] = *(const f32x4*)(bx + (jj0 + jl) * 16 + 4 * q);

  const long stepN = (long)NBATCH * DD;
  const unsigned short* xb = xbf + (long)(blockIdx.x * 16 + m) * DD + 8 * q;
  float* hb = H + (long)(blockIdx.x * 16 + m) * DD;

  auto pref = [&](bf16x8 (&r)[4], int t) {     // 4 x 16B ready-to-use B-frags
    const unsigned short* p = xb + (long)t * stepN;
#pragma unroll
    for (int kq = 0; kq < 4; ++kq) r[kq] = *(const bf16x8*)(p + 32 * kq);
  };

  const f32x4 zz = (f32x4){0.f, 0.f, 0.f, 0.f};

  // carried Wx partial pairs for the CURRENT step t
  f32x4 xw0a, xw0b, xw1a, xw1b;

  auto xw_compute = [&](const bf16x8 (&xf)[4]) {   // depth-2 pairs (R9 order)
    xw0a = __builtin_amdgcn_mfma_f32_16x16x32_bf16(Wxf[0][0], xf[0], bxv[0], 0, 0, 0);
    xw1a = __builtin_amdgcn_mfma_f32_16x16x32_bf16(Wxf[1][0], xf[0], bxv[1], 0, 0, 0);
    xw0b = __builtin_amdgcn_mfma_f32_16x16x32_bf16(Wxf[0][2], xf[2], zz, 0, 0, 0);
    xw1b = __builtin_amdgcn_mfma_f32_16x16x32_bf16(Wxf[1][2], xf[2], zz, 0, 0, 0);
    xw0a = __builtin_amdgcn_mfma_f32_16x16x32_bf16(Wxf[0][1], xf[1], xw0a, 0, 0, 0);
    xw1a = __builtin_amdgcn_mfma_f32_16x16x32_bf16(Wxf[1][1], xf[1], xw1a, 0, 0, 0);
    xw0b = __builtin_amdgcn_mfma_f32_16x16x32_bf16(Wxf[0][3], xf[3], xw0b, 0, 0, 0);
    xw1b = __builtin_amdgcn_mfma_f32_16x16x32_bf16(Wxf[1][3], xf[3], xw1b, 0, 0, 0);
  };

  // step t: xfn = slot holding x_{t+1} (consumed in the barrier shadow)
  auto step = [&](const bf16x8 (&xfn)[4], int t, int par) {
    // --- critical path: exchange -> Wh -> combine -> publish ---
    bf16x8 b0 = __builtin_bit_cast(bf16x8, xchg[par ^ 1][0][lane]);
    bf16x8 b1 = __builtin_bit_cast(bf16x8, xchg[par ^ 1][1][lane]);
    bf16x8 b2 = __builtin_bit_cast(bf16x8, xchg[par ^ 1][2][lane]);
    bf16x8 b3 = __builtin_bit_cast(bf16x8, xchg[par ^ 1][3][lane]);

    f32x4 h0a = __builtin_amdgcn_mfma_f32_16x16x32_bf16(Whf[0][0], b0, zz, 0, 0, 0);
    f32x4 h1a = __builtin_amdgcn_mfma_f32_16x16x32_bf16(Whf[1][0], b0, zz, 0, 0, 0);
    f32x4 h0b = __builtin_amdgcn_mfma_f32_16x16x32_bf16(Whf[0][2], b2, zz, 0, 0, 0);
    f32x4 h1b = __builtin_amdgcn_mfma_f32_16x16x32_bf16(Whf[1][2], b2, zz, 0, 0, 0);
    h0a = __builtin_amdgcn_mfma_f32_16x16x32_bf16(Whf[0][1], b1, h0a, 0, 0, 0);
    h1a = __builtin_amdgcn_mfma_f32_16x16x32_bf16(Whf[1][1], b1, h1a, 0, 0, 0);
    h0b = __builtin_amdgcn_mfma_f32_16x16x32_bf16(Whf[0][3], b3, h0b, 0, 0, 0);
    h1b = __builtin_amdgcn_mfma_f32_16x16x32_bf16(Whf[1][3], b3, h1b, 0, 0, 0);

    f32x4 s0 = (xw0a + xw0b) + (h0a + h0b);
    f32x4 s1 = (xw1a + xw1b) + (h1a + h1b);
    f32x4 h0, h1;
#pragma unroll
    for (int r = 0; r < 4; ++r) { h0[r] = fmaxf(s0[r], 0.f); h1[r] = fmaxf(s1[r], 0.f); }

    u32x4 own;
    own[0] = cvtpk_bf16(h0[0], h0[1]); own[1] = cvtpk_bf16(h0[2], h0[3]);
    own[2] = cvtpk_bf16(h1[0], h1[1]); own[3] = cvtpk_bf16(h1[2], h1[3]);
    xchg[par][wv][lane] = own;

    asm volatile("s_waitcnt lgkmcnt(0)" ::: "memory");  // ds_write visible; NO vmcnt drain
    __builtin_amdgcn_s_barrier();
    __builtin_amdgcn_sched_barrier(0);                  // next step's e-reads stay after barrier

    // --- barrier shadow: h-independent work for t / t+1 ---
    float* hp = hb + (long)t * stepN;
    *(f32x4*)(hp + (jj0 + 0) * 16 + 4 * q) = h0;
    *(f32x4*)(hp + (jj0 + 1) * 16 + 4 * q) = h1;
    xw_compute(xfn);                                    // Wx partials for t+1
  };

  bf16x8 sA[4], sB[4], sC[4], sD[4];   // named 4-slot x ring
  pref(sA, 0);
  pref(sB, 1); pref(sC, 2); pref(sD, 3);
  xw_compute(sA);                      // xw for t=0
  pref(sA, 4);                         // slot A now carries x_4

#pragma unroll 1
  for (int t = 0; t < T_STEPS; t += 4) {
    step(sB, t, 0);     pref(sB, t + 5 < T_STEPS ? t + 5 : T_STEPS - 1);
    step(sC, t + 1, 1); pref(sC, t + 6 < T_STEPS ? t + 6 : T_STEPS - 1);
    step(sD, t + 2, 0); pref(sD, t + 7 < T_STEPS ? t + 7 : T_STEPS - 1);
    step(sA, t + 3, 1); pref(sA, t + 8 < T_STEPS ? t + 8 : T_STEPS - 1);
  }
}

// ---------------------------------------------------------------------------
extern "C" void kernel_launch(void* const* d_in, const int* in_sizes, int n_in,
                              void* d_out, int out_size, void* d_ws, size_t ws_size,
                              hipStream_t stream) {
  const float* x  = (const float*)d_in[0];   // (T,N,C)
  const float* Wx = (const float*)d_in[1];   // (D,C)
  const float* bx = (const float*)d_in[2];   // (D)
  const float* Wh = (const float*)d_in[3];   // (D,D)
  const float* Wy = (const float*)d_in[4];   // (K,D)
  const float* by = (const float*)d_in[5];   // (K)

  float* Y = (float*)d_out;        // all_y: [T][N][K]
  float* H = (float*)d_out + TND;  // all_h: [T][N][D]

  // bf16 x staging lives in the Y region (32MB in 64MB); GEMM-Y overwrites
  // it only after the scan has fully consumed it (same-stream ordering).
  unsigned short* xbf = (unsigned short*)Y;

  const int ntiles = T_STEPS * NBATCH / 16;  // 8192 row-tiles

  cvt_x_bf16<<<2048, 256, 0, stream>>>(x, xbf, TND / 8);               // x -> bf16
  rnn_scan_fused<<<NBATCH / 16, 256, 0, stream>>>(xbf, Wx, bx, Wh, H); // -> all_h
  gemm128_yT<<<512, 256, 0, stream>>>(H, Wy, by, Y, ntiles);           // -> all_y
}